// Round 1
// baseline (10108.268 us; speedup 1.0000x reference)
//
#include <hip/hip_runtime.h>
#include <math.h>

#define NN 8192
#define MM 8192
#define FD 128
#define NITER 100

struct Consts {
  float inv_temp, B;
  float lmu_main, lmu_eps, lmu_dust;
  float lnu_main, lnu_eps, lnu_dust;
  int overlap;
};

__device__ __forceinline__ unsigned fenc(float f){
  unsigned u = __float_as_uint(f);
  return (u & 0x80000000u) ? ~u : (u | 0x80000000u);
}
__device__ __forceinline__ float fdec(unsigned e){
  return __uint_as_float((e & 0x80000000u) ? (e ^ 0x80000000u) : ~e);
}
__device__ __forceinline__ void lse_add(float& m, float& s, float x){
  float nm = fmaxf(m, x);
  s = s * __expf(m - nm) + __expf(x - nm);
  m = nm;
}
__device__ __forceinline__ void lse_merge(float& m, float& s, float mo, float so){
  float nm = fmaxf(m, mo);
  s = s * __expf(m - nm) + so * __expf(mo - nm);
  m = nm;
}
__device__ __forceinline__ void block_lse_reduce(float& m, float& s, float* rm, float* rs, int t){
  #pragma unroll
  for (int off = 32; off; off >>= 1){
    float mo = __shfl_down(m, off);
    float so = __shfl_down(s, off);
    lse_merge(m, s, mo, so);
  }
  if ((t & 63) == 0){ rm[t >> 6] = m; rs[t >> 6] = s; }
  __syncthreads();
  if (t == 0){
    m = rm[0]; s = rs[0];
    #pragma unroll
    for (int w = 1; w < 4; w++) lse_merge(m, s, rm[w], rs[w]);
  }
}

__global__ void const_kernel(const float* lt, const float* db, const int* ovp,
                             Consts* C, unsigned* se){
  if (threadIdx.x == 0){
    float temp = fmaxf(expf(lt[0]), 1e-9f);
    C->inv_temp = 1.0f / temp;
    C->B = db[0];
    int ov = ovp[0];
    C->overlap = ov;
    int us = NN - ov > 0 ? NN - ov : 0;
    int ut = MM - ov > 0 ? MM - ov : 0;
    float mud = (float)fmax((double)ut * 0.3, 1e-9);
    float nud = (float)fmax((double)us * 0.3, 1e-9);
    int ones_mu = us > 0 ? ov : NN;
    int ones_nu = ut > 0 ? ov : MM;
    double Zmu = (double)ones_mu + (double)(NN - ones_mu) * 1e-9 + (double)mud;
    double Znu = (double)ones_nu + (double)(MM - ones_nu) * 1e-9 + (double)nud;
    C->lmu_main = (float)log(1.0 / Zmu);
    C->lmu_eps  = (float)log(1e-9 / Zmu);
    C->lmu_dust = (float)log((double)mud / Zmu);
    C->lnu_main = (float)log(1.0 / Znu);
    C->lnu_eps  = (float)log(1e-9 / Znu);
    C->lnu_dust = (float)log((double)nud / Znu);
    *se = 0u;
  }
}

__global__ __launch_bounds__(128) void mlp_kernel(const float* __restrict__ x,
    const float* __restrict__ w1, const float* __restrict__ b1,
    const float* __restrict__ w2, const float* __restrict__ b2,
    const float* __restrict__ w3, const float* __restrict__ b3,
    float* __restrict__ feat, float* __restrict__ norms){
  __shared__ float h1[64];
  __shared__ float h2[128];
  __shared__ float nr[2];
  int p = blockIdx.x, t = threadIdx.x;
  float x0 = x[p * 3 + 0], x1 = x[p * 3 + 1], x2 = x[p * 3 + 2];
  if (t < 64){
    float a = x0 * w1[t] + x1 * w1[64 + t] + x2 * w1[128 + t] + b1[t];
    h1[t] = fmaxf(a, 0.f);
  }
  __syncthreads();
  float a = b2[t];
  #pragma unroll 8
  for (int k = 0; k < 64; k++) a = fmaf(h1[k], w2[k * 128 + t], a);
  h2[t] = fmaxf(a, 0.f);
  __syncthreads();
  float o = b3[t];
  #pragma unroll 8
  for (int k = 0; k < 128; k++) o = fmaf(h2[k], w3[k * 128 + t], o);
  feat[(size_t)p * FD + t] = o;
  float q = o * o;
  #pragma unroll
  for (int off = 32; off; off >>= 1) q += __shfl_down(q, off);
  if ((t & 63) == 0) nr[t >> 6] = q;
  __syncthreads();
  if (t == 0) norms[p] = nr[0] + nr[1];
}

// swizzled LDS index: float4 chunk k4 of row r
__device__ __forceinline__ int swz(int r, int k4){
  return r * FD + ((k4 ^ ((r >> 2) & 7)) << 2);
}

__global__ __launch_bounds__(256) void score_kernel(const float* __restrict__ af,
    const float* __restrict__ bf, const float* __restrict__ na, const float* __restrict__ nb,
    const Consts* __restrict__ C, float* __restrict__ S, unsigned* __restrict__ se){
  __shared__ float As[64 * FD];
  __shared__ float Bs[64 * FD];
  __shared__ float wm[4];
  int i0 = blockIdx.y * 64, j0 = blockIdx.x * 64;
  int tid = threadIdx.x;
  #pragma unroll
  for (int cc = 0; cc < 8; cc++){
    int lin = cc * 1024 + tid * 4;
    int r = lin >> 7;
    int k = lin & 127;
    int k4 = k >> 2;
    float4 av = *(const float4*)&af[(size_t)(i0 + r) * FD + k];
    float4 bv = *(const float4*)&bf[(size_t)(j0 + r) * FD + k];
    *(float4*)&As[swz(r, k4)] = av;
    *(float4*)&Bs[swz(r, k4)] = bv;
  }
  __syncthreads();
  int tx = tid & 15, ty = tid >> 4;
  int r0 = ty * 4, c0 = tx * 4;
  float acc[4][4];
  #pragma unroll
  for (int a_ = 0; a_ < 4; a_++)
    #pragma unroll
    for (int b_ = 0; b_ < 4; b_++) acc[a_][b_] = 0.f;
  #pragma unroll 4
  for (int k = 0; k < FD; k += 4){
    float4 av[4], bv[4];
    #pragma unroll
    for (int q = 0; q < 4; q++){
      av[q] = *(const float4*)&As[swz(r0 + q, k >> 2)];
      bv[q] = *(const float4*)&Bs[swz(c0 + q, k >> 2)];
    }
    #pragma unroll
    for (int a_ = 0; a_ < 4; a_++)
      #pragma unroll
      for (int b_ = 0; b_ < 4; b_++){
        acc[a_][b_] = fmaf(av[a_].x, bv[b_].x, acc[a_][b_]);
        acc[a_][b_] = fmaf(av[a_].y, bv[b_].y, acc[a_][b_]);
        acc[a_][b_] = fmaf(av[a_].z, bv[b_].z, acc[a_][b_]);
        acc[a_][b_] = fmaf(av[a_].w, bv[b_].w, acc[a_][b_]);
      }
  }
  float inv_t = C->inv_temp;
  float tmax = -INFINITY;
  #pragma unroll
  for (int a_ = 0; a_ < 4; a_++){
    float nai = na[i0 + r0 + a_];
    float4 out;
    float* op = &out.x;
    #pragma unroll
    for (int b_ = 0; b_ < 4; b_++){
      float d2 = nai + nb[j0 + c0 + b_] - 2.0f * acc[a_][b_];
      d2 = fmaxf(d2, 0.f);
      float sc = -sqrtf(d2) * inv_t;
      op[b_] = sc;
      tmax = fmaxf(tmax, sc);
    }
    *(float4*)&S[(size_t)(i0 + r0 + a_) * MM + j0 + c0] = out;
  }
  #pragma unroll
  for (int off = 32; off; off >>= 1) tmax = fmaxf(tmax, __shfl_down(tmax, off));
  if ((tid & 63) == 0) wm[tid >> 6] = tmax;
  __syncthreads();
  if (tid == 0){
    float mm = fmaxf(fmaxf(wm[0], wm[1]), fmaxf(wm[2], wm[3]));
    atomicMax(se, fenc(mm));
  }
}

__global__ __launch_bounds__(256) void row_kernel(const float* __restrict__ S,
    const float* __restrict__ v, float* __restrict__ u,
    const Consts* __restrict__ C, const unsigned* __restrict__ se){
  __shared__ float rm[4], rs[4];
  int i = blockIdx.x, t = threadIdx.x;
  float smax = fdec(*se);
  if (i == NN){
    float m = -INFINITY, s = 0.f;
    for (int j = t; j <= MM; j += 256) lse_add(m, s, v[j]);
    block_lse_reduce(m, s, rm, rs, t);
    if (t == 0) u[NN] = C->lmu_dust - (C->B + m + __logf(s));
    return;
  }
  const float4* Sr = (const float4*)(S + (size_t)i * MM);
  const float4* Vr = (const float4*)v;
  float4 val[8];
  float m = -INFINITY;
  #pragma unroll
  for (int c = 0; c < 8; c++){
    float4 a = Sr[c * 256 + t];
    float4 w = Vr[c * 256 + t];
    float4 x;
    x.x = a.x - smax + w.x;
    x.y = a.y - smax + w.y;
    x.z = a.z - smax + w.z;
    x.w = a.w - smax + w.w;
    val[c] = x;
    m = fmaxf(m, fmaxf(fmaxf(x.x, x.y), fmaxf(x.z, x.w)));
  }
  #pragma unroll
  for (int off = 32; off; off >>= 1) m = fmaxf(m, __shfl_xor(m, off));
  if ((t & 63) == 0) rm[t >> 6] = m;
  __syncthreads();
  m = fmaxf(fmaxf(rm[0], rm[1]), fmaxf(rm[2], rm[3]));
  float s = 0.f;
  #pragma unroll
  for (int c = 0; c < 8; c++){
    s += __expf(val[c].x - m) + __expf(val[c].y - m)
       + __expf(val[c].z - m) + __expf(val[c].w - m);
  }
  #pragma unroll
  for (int off = 32; off; off >>= 1) s += __shfl_xor(s, off);
  if ((t & 63) == 0) rs[t >> 6] = s;
  __syncthreads();
  if (t == 0){
    s = rs[0] + rs[1] + rs[2] + rs[3];
    float x = C->B + v[MM];
    float nm = fmaxf(m, x);
    float s2 = s * __expf(m - nm) + __expf(x - nm);
    float lmu = (i < C->overlap) ? C->lmu_main : C->lmu_eps;
    u[i] = lmu - (nm + __logf(s2));
  }
}

__global__ __launch_bounds__(256) void colp_kernel(const float* __restrict__ S,
    const float* __restrict__ u, float* __restrict__ pm, float* __restrict__ ps,
    const unsigned* __restrict__ se){
  float smax = fdec(*se);
  int j0 = blockIdx.x * 1024 + threadIdx.x * 4;
  int i0 = blockIdx.y * 64;
  float m0 = -INFINITY, m1 = -INFINITY, m2 = -INFINITY, m3 = -INFINITY;
  float s0 = 0.f, s1 = 0.f, s2 = 0.f, s3 = 0.f;
  #pragma unroll 4
  for (int r = 0; r < 64; r++){
    int i = i0 + r;
    float c = u[i] - smax;
    float4 a = *(const float4*)&S[(size_t)i * MM + j0];
    { float x = a.x + c; float nm = fmaxf(m0, x); s0 = s0 * __expf(m0 - nm) + __expf(x - nm); m0 = nm; }
    { float x = a.y + c; float nm = fmaxf(m1, x); s1 = s1 * __expf(m1 - nm) + __expf(x - nm); m1 = nm; }
    { float x = a.z + c; float nm = fmaxf(m2, x); s2 = s2 * __expf(m2 - nm) + __expf(x - nm); m2 = nm; }
    { float x = a.w + c; float nm = fmaxf(m3, x); s3 = s3 * __expf(m3 - nm) + __expf(x - nm); m3 = nm; }
  }
  size_t o = (size_t)blockIdx.y * MM + j0;
  *(float4*)&pm[o] = make_float4(m0, m1, m2, m3);
  *(float4*)&ps[o] = make_float4(s0, s1, s2, s3);
}

__global__ __launch_bounds__(256) void colc_kernel(const float* __restrict__ pm,
    const float* __restrict__ ps, const float* __restrict__ u, float* __restrict__ v,
    const Consts* __restrict__ C){
  __shared__ float rm[4], rs[4];
  int b = blockIdx.x, t = threadIdx.x;
  if (b < 32){
    int j = b * 256 + t;
    float m = -INFINITY, s = 0.f;
    for (int rc = 0; rc < 128; rc++){
      lse_merge(m, s, pm[(size_t)rc * MM + j], ps[(size_t)rc * MM + j]);
    }
    lse_add(m, s, C->B + u[NN]);
    float lnu = (j < C->overlap) ? C->lnu_main : C->lnu_eps;
    v[j] = lnu - (m + __logf(s));
  } else {
    float m = -INFINITY, s = 0.f;
    for (int i = t; i <= NN; i += 256) lse_add(m, s, u[i]);
    block_lse_reduce(m, s, rm, rs, t);
    if (t == 0) v[MM] = C->lnu_dust - (C->B + m + __logf(s));
  }
}

__global__ __launch_bounds__(256) void trans_kernel(float* __restrict__ S,
    const float* __restrict__ u, const float* __restrict__ v,
    const unsigned* __restrict__ se){
  size_t lin = ((size_t)blockIdx.x * 256 + threadIdx.x) * 4;
  int i = (int)(lin >> 13);
  int j = (int)(lin & (size_t)(MM - 1));
  float c = u[i] - fdec(*se);
  float4 a = *(float4*)&S[lin];
  const float4 w = *(const float4*)&v[j];
  a.x = __expf(a.x + c + w.x);
  a.y = __expf(a.y + c + w.y);
  a.z = __expf(a.z + c + w.z);
  a.w = __expf(a.w + c + w.w);
  *(float4*)&S[lin] = a;
}

__global__ __launch_bounds__(256) void dustbin_kernel(float* __restrict__ out,
    const float* __restrict__ u, const float* __restrict__ v,
    const Consts* __restrict__ C){
  int idx = blockIdx.x * 256 + threadIdx.x;
  float B = C->B;
  if (idx < NN){
    out[(size_t)NN * MM + idx] = __expf(B + u[idx] + v[MM]);
  } else {
    int j = idx - NN;
    out[(size_t)NN * MM + NN + j] = __expf(B + u[NN] + v[j]);
  }
}

extern "C" void kernel_launch(void* const* d_in, const int* in_sizes, int n_in,
                              void* d_out, int out_size, void* d_ws, size_t ws_size,
                              hipStream_t stream){
  const float* source = (const float*)d_in[0];
  const float* target = (const float*)d_in[1];
  const float* sw1 = (const float*)d_in[2];
  const float* sb1 = (const float*)d_in[3];
  const float* sw2 = (const float*)d_in[4];
  const float* sb2 = (const float*)d_in[5];
  const float* sw3 = (const float*)d_in[6];
  const float* sb3 = (const float*)d_in[7];
  const float* tw1 = (const float*)d_in[8];
  const float* tb1 = (const float*)d_in[9];
  const float* tw2 = (const float*)d_in[10];
  const float* tb2 = (const float*)d_in[11];
  const float* tw3 = (const float*)d_in[12];
  const float* tb3 = (const float*)d_in[13];
  const float* lt  = (const float*)d_in[14];
  const float* db  = (const float*)d_in[15];
  const int*   ovp = (const int*)d_in[16];

  float* S  = (float*)d_out;
  float* ws = (float*)d_ws;
  Consts* C = (Consts*)ws;
  unsigned* se = (unsigned*)(ws + 32);
  float* u  = ws + 64;
  float* v  = u + 8448;
  float* A0 = v + 8448;
  float* sfeat = A0;
  float* tfeat = A0 + (size_t)NN * FD;
  float* na = A0 + 2 * (size_t)NN * FD;
  float* nb = na + NN;
  float* pm = A0;
  float* psum = A0 + (size_t)128 * MM;

  hipMemsetAsync(u, 0, sizeof(float) * 2 * 8448, stream);
  const_kernel<<<1, 64, 0, stream>>>(lt, db, ovp, C, se);
  mlp_kernel<<<NN, 128, 0, stream>>>(source, sw1, sb1, sw2, sb2, sw3, sb3, sfeat, na);
  mlp_kernel<<<MM, 128, 0, stream>>>(target, tw1, tb1, tw2, tb2, tw3, tb3, tfeat, nb);
  score_kernel<<<dim3(MM / 64, NN / 64), 256, 0, stream>>>(sfeat, tfeat, na, nb, C, S, se);
  for (int it = 0; it < NITER; ++it){
    row_kernel<<<NN + 1, 256, 0, stream>>>(S, v, u, C, se);
    colp_kernel<<<dim3(8, 128), 256, 0, stream>>>(S, u, pm, psum, se);
    colc_kernel<<<33, 256, 0, stream>>>(pm, psum, u, v, C);
  }
  trans_kernel<<<(int)(((size_t)NN * MM) / 1024), 256, 0, stream>>>(S, u, v, se);
  dustbin_kernel<<<(2 * NN) / 256, 256, 0, stream>>>((float*)d_out, u, v, C);
}